// Round 10
// baseline (3278.732 us; speedup 1.0000x reference)
//
#include <hip/hip_runtime.h>
#include <math.h>

#define HH 512
#define DD 512
#define BB 64
#define SS 256
#define KK 1024
#define CC 5

typedef __attribute__((ext_vector_type(8))) short short8;
typedef __attribute__((ext_vector_type(4))) float float4v;

// ---- workspace layout (bytes) ----  total 101,188,608 B
#define OFF_XEF     0u               // 256 s x 2 sp x 64 b x 512 k shorts = 33.5 MB
#define OFF_HSPL    33554432u        // [2 sp][2 phase][2 dir][64 b][512 k] shorts
#define OFF_FLG     34078720u        // 256 x 4B flags
#define OFF_HIST    34079744u        // 2 x 256 x 512 x 64 fp32 = 67 MB
#define OFF_POOLED  OFF_HSPL         // pooled overlays hspl (dead after recurrence)
#define HSPL_PLANE  131072           // shorts per split plane

__device__ __forceinline__ unsigned f2bf_bits(float f) {
    unsigned u = __builtin_bit_cast(unsigned, f);
    return (u + 0x7fffu + ((u >> 16) & 1u)) >> 16;   // RNE
}
__device__ __forceinline__ float sigm_(float v) {
    return 1.f / (1.f + expf(-v));
}
__device__ __forceinline__ float tanh_(float v) {
    return tanhf(v);
}

// ---------------------------------------------------------------------------
// Gather embeddings + split hi/lo bf16 into xef[s][sp][b][k].
// ---------------------------------------------------------------------------
__global__ __launch_bounds__(256)
void gather_split_k(const int* __restrict__ x, const float* __restrict__ embed,
                    short* __restrict__ xef)
{
    const int s   = blockIdx.x;
    const int tid = threadIdx.x;
    const int b   = tid & 63;
    const int seg = tid >> 6;            // 4 segs x 128 k
    __shared__ int rows[BB];
    if (tid < BB) rows[tid] = x[tid * SS + s];   // x is [B][S]
    __syncthreads();
    const float* e = embed + (size_t)rows[b] * DD + seg * 128;
    short* oh = xef + ((size_t)(s * 2 + 0) * BB + b) * 512 + seg * 128;
    short* ol = xef + ((size_t)(s * 2 + 1) * BB + b) * 512 + seg * 128;
    for (int k0 = 0; k0 < 128; k0 += 8) {
        const float4 a = *(const float4*)(e + k0);
        const float4 c = *(const float4*)(e + k0 + 4);
        const float ev[8] = {a.x, a.y, a.z, a.w, c.x, c.y, c.z, c.w};
        short8 vh, vl;
        #pragma unroll
        for (int j = 0; j < 8; ++j) {
            const unsigned hib = f2bf_bits(ev[j]);
            const float hif = __builtin_bit_cast(float, hib << 16);
            const unsigned lob = f2bf_bits(ev[j] - hif);
            vh[j] = (short)hib;
            vl[j] = (short)lob;
        }
        *(short8*)(oh + k0) = vh;
        *(short8*)(ol + k0) = vl;
    }
}

// ---------------------------------------------------------------------------
__global__ __launch_bounds__(256)
void zero_k(unsigned* __restrict__ base, int ndw)
{
    int i = blockIdx.x * 256 + threadIdx.x;
    const int stride = gridDim.x * 256;
    for (; i < ndw; i += stride) base[i] = 0u;
}

// ---------------------------------------------------------------------------
// Cooperative recurrence: 256 WGs x 256 thr (1 WG/CU). R17 = R16 with the
// macro name collision fixed (base pointers renamed xhp/xlp; XDECL(8) used
// to collide with the old pointer name xh8). Single change vs R8-proven:
// the x-part's 32 16B loads are issued as ONE named batch BEFORE the spin
// (xef misses the 4MB per-XCD L2 — FETCH_SIZE 522MB = 8 XCD x 64MB re-fetch
// — so these are ~650cy LLC loads at compiler depth ~2-3; batching raises
// depth to 32; normal cached loads have NO coherent cap, unlike the h-path
// whose batching was proven null in R8). x-MFMAs stay in place after the
// spin, reading named registers in the bit-identical order (kt ascending,
// whi*xh / whi*xl / wlo*xh). h-part, spin, exchange, publish, flag:
// byte-identical to R8.
// ---------------------------------------------------------------------------
__global__ void __launch_bounds__(256, 1)
bilstm_recur_k(const short* __restrict__ xef,
               const float* __restrict__ fwd_W, const float* __restrict__ bwd_W,
               const float* __restrict__ fwd_b, const float* __restrict__ bwd_b,
               short* __restrict__ hspl, float* __restrict__ hist,
               unsigned* __restrict__ flg)
{
    extern __shared__ char smem[];
    short8* wlds = (short8*)smem;                          // 64 KB W fragments
    float*  ex   = (float*)(smem + 65536);                 // 4 KB exchange
    unsigned short* stg = (unsigned short*)(smem + 69632); // 1 KB publish stage

    const int w      = blockIdx.x;
    const int dir    = w >> 7;
    const int wlocal = w & 127;
    const int h0     = wlocal << 2;
    const int tid    = threadIdx.x;
    const int lane   = tid & 63;
    const int wv     = __builtin_amdgcn_readfirstlane(tid >> 6);
    const int n0     = wv << 4;
    const int nn     = lane & 15;
    const int quad   = lane >> 4;

    // ---- pack this WG's W fragments straight into LDS (bit-identical to
    //      wpack_k: f2bf_bits split of W[(g*H+h0+hh)][kt*32+quad*8+j]) ----
    {
        const float* W = dir ? bwd_W : fwd_W;
        const int m  = lane & 15;
        const int g  = m >> 2;
        const int hh = m & 3;
        const float* wrow = W + ((size_t)g * HH + h0 + hh) * KK + quad * 8;
        for (int kk = 0; kk < 8; ++kk) {
            const int kt = wv * 8 + kk;          // 4 waves x 8 = 32 kt
            const float4 a  = *(const float4*)(wrow + kt * 32);
            const float4 c4 = *(const float4*)(wrow + kt * 32 + 4);
            const float ev[8] = {a.x, a.y, a.z, a.w, c4.x, c4.y, c4.z, c4.w};
            short8 vh, vl;
            #pragma unroll
            for (int j = 0; j < 8; ++j) {
                const unsigned hib = f2bf_bits(ev[j]);
                const float hif = __builtin_bit_cast(float, hib << 16);
                const unsigned lob = f2bf_bits(ev[j] - hif);
                vh[j] = (short)hib;
                vl[j] = (short)lob;
            }
            wlds[(0 * 32 + kt) * 64 + lane] = vh;
            wlds[(1 * 32 + kt) * 64 + lane] = vl;
        }
    }
    __syncthreads();

    const float* bi = dir ? bwd_b : fwd_b;
    const float4 biasv = *(const float4*)(bi + quad * HH + h0);
    const float bias_arr[4] = {biasv.x, biasv.y, biasv.z, biasv.w};

    unsigned* myflg = flg + dir * 128;
    float* exw = ex + wv * 256;
    const int b = n0 + nn;
    const int h = h0 + quad;

    for (int t = 0; t < SS; ++t) {
        const int s = dir ? (SS - 1 - t) : t;
        const int p = t & 1;

        float4v acc = {0.f, 0.f, 0.f, 0.f};

        {
            // ---------- x-part loads: 32 x 16B issued as ONE named batch
            //            BEFORE the spin (spin time completes them;
            //            exposure collapses from ~12 RTTs to ~1) ----------
            const short8* xhp = (const short8*)(xef +
                ((size_t)(s * 2 + 0) * BB + b) * 512 + quad * 8);
            const short8* xlp = (const short8*)(xef +
                ((size_t)(s * 2 + 1) * BB + b) * 512 + quad * 8);

#define XDECL(i)                                                              \
            const short8 xh##i = xhp[(i) * 4];                                \
            const short8 xl##i = xlp[(i) * 4];

            XDECL(0)  XDECL(1)  XDECL(2)  XDECL(3)
            XDECL(4)  XDECL(5)  XDECL(6)  XDECL(7)
            XDECL(8)  XDECL(9)  XDECL(10) XDECL(11)
            XDECL(12) XDECL(13) XDECL(14) XDECL(15)
#undef XDECL

            // ---------- wait: all WGs of this dir finished step t-1 ----------
            if (t > 0) {
                const unsigned tgt = (unsigned)t;
                unsigned va, vb;
                va = __hip_atomic_load(myflg + lane, __ATOMIC_RELAXED,
                                       __HIP_MEMORY_SCOPE_AGENT);
                vb = __hip_atomic_load(myflg + 64 + lane, __ATOMIC_RELAXED,
                                       __HIP_MEMORY_SCOPE_AGENT);
                while (__any(va < tgt || vb < tgt)) {
                    __builtin_amdgcn_s_sleep(32);
                    va = __hip_atomic_load(myflg + lane, __ATOMIC_RELAXED,
                                           __HIP_MEMORY_SCOPE_AGENT);
                    vb = __hip_atomic_load(myflg + 64 + lane, __ATOMIC_RELAXED,
                                           __HIP_MEMORY_SCOPE_AGENT);
                }
                asm volatile("" ::: "memory");
            }

            // ---------- x-part MFMAs (bit-identical order to R3/R8) ----------
#define XMFMA(i)                                                              \
            {                                                                 \
                const short8 whi = wlds[(0 * 32 + (i)) * 64 + lane];          \
                const short8 wlo = wlds[(1 * 32 + (i)) * 64 + lane];          \
                acc = __builtin_amdgcn_mfma_f32_16x16x32_bf16(whi, xh##i, acc, 0, 0, 0); \
                acc = __builtin_amdgcn_mfma_f32_16x16x32_bf16(whi, xl##i, acc, 0, 0, 0); \
                acc = __builtin_amdgcn_mfma_f32_16x16x32_bf16(wlo, xh##i, acc, 0, 0, 0); \
            }

            XMFMA(0)  XMFMA(1)  XMFMA(2)  XMFMA(3)
            XMFMA(4)  XMFMA(5)  XMFMA(6)  XMFMA(7)
            XMFMA(8)  XMFMA(9)  XMFMA(10) XMFMA(11)
            XMFMA(12) XMFMA(13) XMFMA(14) XMFMA(15)
#undef XMFMA
        }

        // ---------- h-part: 64 agent-scope 8B loads issued as ONE batch
        //            into named registers, then 16 MFMA groups (R8 text) ----
        {
            const size_t zrow = ((size_t)(p * 2 + dir) * BB + b) * HH + quad * 8;
            const unsigned long long* zhq = (const unsigned long long*)(hspl + zrow);
            const unsigned long long* zlq =
                (const unsigned long long*)(hspl + HSPL_PLANE + zrow);

#define HDECL(i)                                                              \
            const unsigned long long ha##i =                                  \
                __hip_atomic_load(zhq + (i) * 8 + 0, __ATOMIC_RELAXED,        \
                                  __HIP_MEMORY_SCOPE_AGENT);                  \
            const unsigned long long hb##i =                                  \
                __hip_atomic_load(zhq + (i) * 8 + 1, __ATOMIC_RELAXED,        \
                                  __HIP_MEMORY_SCOPE_AGENT);                  \
            const unsigned long long hc##i =                                  \
                __hip_atomic_load(zlq + (i) * 8 + 0, __ATOMIC_RELAXED,        \
                                  __HIP_MEMORY_SCOPE_AGENT);                  \
            const unsigned long long hd##i =                                  \
                __hip_atomic_load(zlq + (i) * 8 + 1, __ATOMIC_RELAXED,        \
                                  __HIP_MEMORY_SCOPE_AGENT);

            HDECL(0)  HDECL(1)  HDECL(2)  HDECL(3)
            HDECL(4)  HDECL(5)  HDECL(6)  HDECL(7)
            HDECL(8)  HDECL(9)  HDECL(10) HDECL(11)
            HDECL(12) HDECL(13) HDECL(14) HDECL(15)
#undef HDECL

#define HMFMA(i)                                                              \
            {                                                                 \
                union { unsigned long long q[2]; short8 v; } uh, ul;          \
                uh.q[0] = ha##i; uh.q[1] = hb##i;                             \
                ul.q[0] = hc##i; ul.q[1] = hd##i;                             \
                const short8 whi = wlds[(0 * 32 + 16 + (i)) * 64 + lane];     \
                const short8 wlo = wlds[(1 * 32 + 16 + (i)) * 64 + lane];     \
                acc = __builtin_amdgcn_mfma_f32_16x16x32_bf16(whi, uh.v, acc, 0, 0, 0); \
                acc = __builtin_amdgcn_mfma_f32_16x16x32_bf16(whi, ul.v, acc, 0, 0, 0); \
                acc = __builtin_amdgcn_mfma_f32_16x16x32_bf16(wlo, uh.v, acc, 0, 0, 0); \
            }

            HMFMA(0)  HMFMA(1)  HMFMA(2)  HMFMA(3)
            HMFMA(4)  HMFMA(5)  HMFMA(6)  HMFMA(7)
            HMFMA(8)  HMFMA(9)  HMFMA(10) HMFMA(11)
            HMFMA(12) HMFMA(13) HMFMA(14) HMFMA(15)
#undef HMFMA
        }

        // ---------- bias + per-wave exchange ----------
        #pragma unroll
        for (int r2 = 0; r2 < 4; ++r2)
            exw[(quad * 4 + r2) * 16 + nn] = acc[r2] + bias_arr[r2];
        float pg[4];
        #pragma unroll
        for (int g_ = 0; g_ < 4; ++g_)
            pg[g_] = exw[(g_ * 4 + quad) * 16 + nn];

        const float f_  = sigm_(pg[0]);
        const float i_  = sigm_(pg[1]);
        const float ct  = tanh_(pg[2]);
        const float o_  = sigm_(pg[3]);
        const float c_  = (f_ + i_) * ct;      // faithful: prev cell unused
        const float hn  = o_ * tanh_(c_);

        const unsigned hib = f2bf_bits(hn);
        const float hif = __builtin_bit_cast(float, hib << 16);
        const unsigned lob = f2bf_bits(hn - hif);
        stg[(0 * 4 + quad) * 64 + b] = (unsigned short)hib;
        stg[(1 * 4 + quad) * 64 + b] = (unsigned short)lob;
        hist[(((size_t)dir * SS + s) * HH + h) * BB + b] = hn;
        __syncthreads();

        // ---------- publish: packed dword write-through stores ----------
        {
            const int plane = tid >> 7;          // 0 hi, 1 lo
            const int d     = tid & 127;
            const int pb    = d >> 1;
            const int pair  = d & 1;
            const unsigned v0 = stg[(plane * 4 + pair * 2 + 0) * 64 + pb];
            const unsigned v1 = stg[(plane * 4 + pair * 2 + 1) * 64 + pb];
            const unsigned val = v0 | (v1 << 16);
            const size_t soff = ((size_t)((p ^ 1) * 2 + dir) * BB + pb) * HH
                                + h0 + pair * 2;
            unsigned* dst = (unsigned*)(hspl + (size_t)plane * HSPL_PLANE + soff);
            __hip_atomic_store(dst, val, __ATOMIC_RELAXED,
                               __HIP_MEMORY_SCOPE_AGENT);
        }
        asm volatile("s_waitcnt vmcnt(0)" ::: "memory");
        __syncthreads();
        if (tid == 0)
            __hip_atomic_store(myflg + wlocal, (unsigned)(t + 1),
                               __ATOMIC_RELAXED, __HIP_MEMORY_SCOPE_AGENT);
    }
}

// ---------------------------------------------------------------------------
__global__ __launch_bounds__(256)
void pool_k(const float* __restrict__ hist, float* __restrict__ pooled)
{
    const int i = blockIdx.x * 256 + threadIdx.x;   // i = h*64 + b
    float m = -2.0f;
    for (int s = 0; s < SS; ++s) {
        const float a = hist[(size_t)s * (HH * BB) + i];
        const float c = hist[(size_t)(SS + s) * (HH * BB) + i];
        m = fmaxf(m, tanhf(a * c));
    }
    pooled[i] = m;
}

__global__ __launch_bounds__(256)
void outgemm_k(const float* __restrict__ pooled, const float* __restrict__ Wout,
               const float* __restrict__ bout, float* __restrict__ out)
{
    const int c   = blockIdx.x;
    const int tid = threadIdx.x;
    const int b   = tid & 63;
    const int q   = __builtin_amdgcn_readfirstlane(tid >> 6);
    float p = 0.0f;
    for (int j = 0; j < 128; ++j) {
        const int h = q * 128 + j;
        p = fmaf(pooled[(size_t)h * BB + b], Wout[c * HH + h], p);
    }
    __shared__ float red[4][BB];
    red[q][b] = p;
    __syncthreads();
    if (tid < BB)
        out[tid * CC + c] = red[0][tid] + red[1][tid] + red[2][tid] + red[3][tid] + bout[c];
}

// ---------------------------------------------------------------------------
extern "C" void kernel_launch(void* const* d_in, const int* in_sizes, int n_in,
                              void* d_out, int out_size, void* d_ws, size_t ws_size,
                              hipStream_t stream)
{
    const int*   x     = (const int*)d_in[0];
    const float* embed = (const float*)d_in[1];
    const float* fwd_W = (const float*)d_in[2];
    const float* fwd_b = (const float*)d_in[3];
    const float* bwd_W = (const float*)d_in[4];
    const float* bwd_b = (const float*)d_in[5];
    const float* Wout  = (const float*)d_in[6];
    const float* bout  = (const float*)d_in[7];
    float* out = (float*)d_out;

    char* wsb = (char*)d_ws;
    short*    xef    = (short*)(wsb + OFF_XEF);
    short*    hspl   = (short*)(wsb + OFF_HSPL);
    unsigned* flg    = (unsigned*)(wsb + OFF_FLG);
    float*    hist   = (float*)(wsb + OFF_HIST);
    float*    pooled = (float*)(wsb + OFF_POOLED);   // overlays hspl (dead)

    gather_split_k<<<SS, 256, 0, stream>>>(x, embed, xef);
    zero_k<<<512, 256, 0, stream>>>((unsigned*)(wsb + OFF_HSPL),
                                    (int)((524288 + 1024) / 4));

    hipFuncSetAttribute((const void*)bilstm_recur_k,
                        hipFuncAttributeMaxDynamicSharedMemorySize, 70656);
    void* args[] = {(void*)&xef, (void*)&fwd_W, (void*)&bwd_W,
                    (void*)&fwd_b, (void*)&bwd_b,
                    (void*)&hspl, (void*)&hist, (void*)&flg};
    hipLaunchCooperativeKernel((void*)bilstm_recur_k, dim3(256), dim3(256),
                               args, 70656, stream);

    pool_k<<<128, 256, 0, stream>>>(hist, pooled);
    outgemm_k<<<CC, 256, 0, stream>>>(pooled, Wout, bout, out);
}

// Round 11
// 2268.906 us; speedup vs baseline: 1.4451x; 1.4451x over previous
//
#include <hip/hip_runtime.h>
#include <math.h>

#define HH 512
#define DD 512
#define BB 64
#define SS 256
#define KK 1024
#define CC 5

typedef __attribute__((ext_vector_type(8))) short short8;
typedef __attribute__((ext_vector_type(4))) float float4v;

// ---- workspace layout (bytes) ----  total 101,188,608 B
#define OFF_XEF     0u               // 256 s x 2 sp x 64 b x 512 k shorts = 33.5 MB
#define OFF_HSPL    33554432u        // [2 sp][2 phase][2 dir][64 b][512 k] shorts
#define OFF_FLG     34078720u        // 256 x 4B flags
#define OFF_HIST    34079744u        // 2 x 256 x 512 x 64 fp32 = 67 MB
#define OFF_POOLED  OFF_HSPL         // pooled overlays hspl (dead after recurrence)
#define HSPL_PLANE  131072           // shorts per split plane

__device__ __forceinline__ unsigned f2bf_bits(float f) {
    unsigned u = __builtin_bit_cast(unsigned, f);
    return (u + 0x7fffu + ((u >> 16) & 1u)) >> 16;   // RNE
}
__device__ __forceinline__ float sigm_(float v) {
    return 1.f / (1.f + expf(-v));
}
__device__ __forceinline__ float tanh_(float v) {
    return tanhf(v);
}

// ---------------------------------------------------------------------------
// Gather embeddings + split hi/lo bf16 into xef[s][sp][b][k].
// ---------------------------------------------------------------------------
__global__ __launch_bounds__(256)
void gather_split_k(const int* __restrict__ x, const float* __restrict__ embed,
                    short* __restrict__ xef)
{
    const int s   = blockIdx.x;
    const int tid = threadIdx.x;
    const int b   = tid & 63;
    const int seg = tid >> 6;            // 4 segs x 128 k
    __shared__ int rows[BB];
    if (tid < BB) rows[tid] = x[tid * SS + s];   // x is [B][S]
    __syncthreads();
    const float* e = embed + (size_t)rows[b] * DD + seg * 128;
    short* oh = xef + ((size_t)(s * 2 + 0) * BB + b) * 512 + seg * 128;
    short* ol = xef + ((size_t)(s * 2 + 1) * BB + b) * 512 + seg * 128;
    for (int k0 = 0; k0 < 128; k0 += 8) {
        const float4 a = *(const float4*)(e + k0);
        const float4 c = *(const float4*)(e + k0 + 4);
        const float ev[8] = {a.x, a.y, a.z, a.w, c.x, c.y, c.z, c.w};
        short8 vh, vl;
        #pragma unroll
        for (int j = 0; j < 8; ++j) {
            const unsigned hib = f2bf_bits(ev[j]);
            const float hif = __builtin_bit_cast(float, hib << 16);
            const unsigned lob = f2bf_bits(ev[j] - hif);
            vh[j] = (short)hib;
            vl[j] = (short)lob;
        }
        *(short8*)(oh + k0) = vh;
        *(short8*)(ol + k0) = vl;
    }
}

// ---------------------------------------------------------------------------
__global__ __launch_bounds__(256)
void zero_k(unsigned* __restrict__ base, int ndw)
{
    int i = blockIdx.x * 256 + threadIdx.x;
    const int stride = gridDim.x * 256;
    for (; i < ndw; i += stride) base[i] = 0u;
}

// ---------------------------------------------------------------------------
// Cooperative recurrence: 256 WGs x 256 thr (1 WG/CU). R18 = R8-proven body
// with the h-part restructured for LINE-COUNT, not depth (every depth/
// batching probe R4/R8/R10 was null; the surviving model is a per-CU
// line-request service limit: the old h-part scattered 64 lanes x 1KB
// stride = 64 lines per instruction, 4096 lines/step/wave). New h-part:
// cooperatively stage the WG's full h slice ([2 planes][64 b][1KB] = 128KB)
// with COALESCED agent-scope 8B loads (adjacent lanes adjacent addresses ->
// 2048 fully-used lines per WG), plane-at-a-time through a 64KB LDS buffer
// (XOR-swizzled vs the 1KB-stride bank conflict), then read MFMA fragments
// from LDS. Coherence protocol unchanged: same agent-scope atomic loads,
// same all-wave spin BEFORE the loads (observer==loader). Accumulation
// order becomes (whi*uh, wlo*uh)x16 then (whi*ul)x16 — rounding-level only.
// x-part, spin, exchange, gates, publish, flag: byte-identical to R8.
// ---------------------------------------------------------------------------
__global__ void __launch_bounds__(256, 1)
bilstm_recur_k(const short* __restrict__ xef,
               const float* __restrict__ fwd_W, const float* __restrict__ bwd_W,
               const float* __restrict__ fwd_b, const float* __restrict__ bwd_b,
               short* __restrict__ hspl, float* __restrict__ hist,
               unsigned* __restrict__ flg)
{
    extern __shared__ char smem[];
    short8* wlds = (short8*)smem;                           // 64 KB W fragments
    char*   hbuf = smem + 65536;                            // 64 KB staged h plane
    float*  ex   = (float*)(smem + 131072);                 // 4 KB exchange
    unsigned short* stg = (unsigned short*)(smem + 135168); // 1 KB publish stage

    const int w      = blockIdx.x;
    const int dir    = w >> 7;
    const int wlocal = w & 127;
    const int h0     = wlocal << 2;
    const int tid    = threadIdx.x;
    const int lane   = tid & 63;
    const int wv     = __builtin_amdgcn_readfirstlane(tid >> 6);
    const int n0     = wv << 4;
    const int nn     = lane & 15;
    const int quad   = lane >> 4;

    // ---- pack this WG's W fragments straight into LDS (bit-identical to
    //      wpack_k: f2bf_bits split of W[(g*H+h0+hh)][kt*32+quad*8+j]) ----
    {
        const float* W = dir ? bwd_W : fwd_W;
        const int m  = lane & 15;
        const int g  = m >> 2;
        const int hh = m & 3;
        const float* wrow = W + ((size_t)g * HH + h0 + hh) * KK + quad * 8;
        for (int kk = 0; kk < 8; ++kk) {
            const int kt = wv * 8 + kk;          // 4 waves x 8 = 32 kt
            const float4 a  = *(const float4*)(wrow + kt * 32);
            const float4 c4 = *(const float4*)(wrow + kt * 32 + 4);
            const float ev[8] = {a.x, a.y, a.z, a.w, c4.x, c4.y, c4.z, c4.w};
            short8 vh, vl;
            #pragma unroll
            for (int j = 0; j < 8; ++j) {
                const unsigned hib = f2bf_bits(ev[j]);
                const float hif = __builtin_bit_cast(float, hib << 16);
                const unsigned lob = f2bf_bits(ev[j] - hif);
                vh[j] = (short)hib;
                vl[j] = (short)lob;
            }
            wlds[(0 * 32 + kt) * 64 + lane] = vh;
            wlds[(1 * 32 + kt) * 64 + lane] = vl;
        }
    }
    __syncthreads();

    const float* bi = dir ? bwd_b : fwd_b;
    const float4 biasv = *(const float4*)(bi + quad * HH + h0);
    const float bias_arr[4] = {biasv.x, biasv.y, biasv.z, biasv.w};

    unsigned* myflg = flg + dir * 128;
    float* exw = ex + wv * 256;
    const int b = n0 + nn;
    const int h = h0 + quad;

    // staging decomposition: thread writes 8B at flat offset tid*8 + it*2048
    // within the 64KB plane slice -> bb = (tid>>7) + it*2, kb = (tid&127)*8
    const int sb0 = tid >> 7;
    const int skb = (tid & 127) * 8;

    for (int t = 0; t < SS; ++t) {
        const int s = dir ? (SS - 1 - t) : t;
        const int p = t & 1;

        float4v acc = {0.f, 0.f, 0.f, 0.f};

        // ---------- x-part: contiguous fragment loads from xef ----------
        {
            const short8* xh8 = (const short8*)(xef +
                ((size_t)(s * 2 + 0) * BB + b) * 512 + quad * 8);
            const short8* xl8 = (const short8*)(xef +
                ((size_t)(s * 2 + 1) * BB + b) * 512 + quad * 8);
            #pragma unroll
            for (int kt = 0; kt < 16; ++kt) {
                const short8 xh  = xh8[kt * 4];
                const short8 xl  = xl8[kt * 4];
                const short8 whi = wlds[(0 * 32 + kt) * 64 + lane];
                const short8 wlo = wlds[(1 * 32 + kt) * 64 + lane];
                acc = __builtin_amdgcn_mfma_f32_16x16x32_bf16(whi, xh, acc, 0, 0, 0);
                acc = __builtin_amdgcn_mfma_f32_16x16x32_bf16(whi, xl, acc, 0, 0, 0);
                acc = __builtin_amdgcn_mfma_f32_16x16x32_bf16(wlo, xh, acc, 0, 0, 0);
            }
        }

        // ---------- wait: all WGs of this dir finished step t-1 ----------
        if (t > 0) {
            const unsigned tgt = (unsigned)t;
            unsigned va, vb;
            va = __hip_atomic_load(myflg + lane, __ATOMIC_RELAXED,
                                   __HIP_MEMORY_SCOPE_AGENT);
            vb = __hip_atomic_load(myflg + 64 + lane, __ATOMIC_RELAXED,
                                   __HIP_MEMORY_SCOPE_AGENT);
            while (__any(va < tgt || vb < tgt)) {
                __builtin_amdgcn_s_sleep(32);
                va = __hip_atomic_load(myflg + lane, __ATOMIC_RELAXED,
                                       __HIP_MEMORY_SCOPE_AGENT);
                vb = __hip_atomic_load(myflg + 64 + lane, __ATOMIC_RELAXED,
                                       __HIP_MEMORY_SCOPE_AGENT);
            }
            asm volatile("" ::: "memory");
        }

        // ---------- h-part: COALESCED cooperative stage -> LDS -> MFMA ----
        {
            const unsigned long long* hq = (const unsigned long long*)
                ((const char*)hspl + (size_t)(p * 2 + dir) * 65536);
            const unsigned long long* lq = (const unsigned long long*)
                ((const char*)hspl + 262144 + (size_t)(p * 2 + dir) * 65536);

            unsigned long long sh[32], sl[32];
            #pragma unroll
            for (int it = 0; it < 32; ++it)
                sh[it] = __hip_atomic_load(hq + tid + it * 256, __ATOMIC_RELAXED,
                                           __HIP_MEMORY_SCOPE_AGENT);
            #pragma unroll
            for (int it = 0; it < 32; ++it)
                sl[it] = __hip_atomic_load(lq + tid + it * 256, __ATOMIC_RELAXED,
                                           __HIP_MEMORY_SCOPE_AGENT);

            // ---- hi plane into swizzled LDS ----
            #pragma unroll
            for (int it = 0; it < 32; ++it) {
                const int bb = sb0 + it * 2;
                *(unsigned long long*)(hbuf +
                    ((bb << 10) | (skb ^ ((bb & 7) << 4)))) = sh[it];
            }
            __syncthreads();
            #pragma unroll
            for (int kt = 0; kt < 16; ++kt) {
                const short8 uh = *(const short8*)(hbuf + ((b << 10) |
                    ((quad * 16 + kt * 64) ^ ((b & 7) << 4))));
                const short8 whi = wlds[(0 * 32 + 16 + kt) * 64 + lane];
                const short8 wlo = wlds[(1 * 32 + 16 + kt) * 64 + lane];
                acc = __builtin_amdgcn_mfma_f32_16x16x32_bf16(whi, uh, acc, 0, 0, 0);
                acc = __builtin_amdgcn_mfma_f32_16x16x32_bf16(wlo, uh, acc, 0, 0, 0);
            }
            __syncthreads();

            // ---- lo plane into swizzled LDS ----
            #pragma unroll
            for (int it = 0; it < 32; ++it) {
                const int bb = sb0 + it * 2;
                *(unsigned long long*)(hbuf +
                    ((bb << 10) | (skb ^ ((bb & 7) << 4)))) = sl[it];
            }
            __syncthreads();
            #pragma unroll
            for (int kt = 0; kt < 16; ++kt) {
                const short8 ul = *(const short8*)(hbuf + ((b << 10) |
                    ((quad * 16 + kt * 64) ^ ((b & 7) << 4))));
                const short8 whi = wlds[(0 * 32 + 16 + kt) * 64 + lane];
                acc = __builtin_amdgcn_mfma_f32_16x16x32_bf16(whi, ul, acc, 0, 0, 0);
            }
        }

        // ---------- bias + per-wave exchange ----------
        #pragma unroll
        for (int r2 = 0; r2 < 4; ++r2)
            exw[(quad * 4 + r2) * 16 + nn] = acc[r2] + bias_arr[r2];
        float pg[4];
        #pragma unroll
        for (int g_ = 0; g_ < 4; ++g_)
            pg[g_] = exw[(g_ * 4 + quad) * 16 + nn];

        const float f_  = sigm_(pg[0]);
        const float i_  = sigm_(pg[1]);
        const float ct  = tanh_(pg[2]);
        const float o_  = sigm_(pg[3]);
        const float c_  = (f_ + i_) * ct;      // faithful: prev cell unused
        const float hn  = o_ * tanh_(c_);

        const unsigned hib = f2bf_bits(hn);
        const float hif = __builtin_bit_cast(float, hib << 16);
        const unsigned lob = f2bf_bits(hn - hif);
        stg[(0 * 4 + quad) * 64 + b] = (unsigned short)hib;
        stg[(1 * 4 + quad) * 64 + b] = (unsigned short)lob;
        hist[(((size_t)dir * SS + s) * HH + h) * BB + b] = hn;
        __syncthreads();

        // ---------- publish: packed dword write-through stores ----------
        {
            const int plane = tid >> 7;          // 0 hi, 1 lo
            const int d     = tid & 127;
            const int pb    = d >> 1;
            const int pair  = d & 1;
            const unsigned v0 = stg[(plane * 4 + pair * 2 + 0) * 64 + pb];
            const unsigned v1 = stg[(plane * 4 + pair * 2 + 1) * 64 + pb];
            const unsigned val = v0 | (v1 << 16);
            const size_t soff = ((size_t)((p ^ 1) * 2 + dir) * BB + pb) * HH
                                + h0 + pair * 2;
            unsigned* dst = (unsigned*)(hspl + (size_t)plane * HSPL_PLANE + soff);
            __hip_atomic_store(dst, val, __ATOMIC_RELAXED,
                               __HIP_MEMORY_SCOPE_AGENT);
        }
        asm volatile("s_waitcnt vmcnt(0)" ::: "memory");
        __syncthreads();
        if (tid == 0)
            __hip_atomic_store(myflg + wlocal, (unsigned)(t + 1),
                               __ATOMIC_RELAXED, __HIP_MEMORY_SCOPE_AGENT);
    }
}

// ---------------------------------------------------------------------------
__global__ __launch_bounds__(256)
void pool_k(const float* __restrict__ hist, float* __restrict__ pooled)
{
    const int i = blockIdx.x * 256 + threadIdx.x;   // i = h*64 + b
    float m = -2.0f;
    for (int s = 0; s < SS; ++s) {
        const float a = hist[(size_t)s * (HH * BB) + i];
        const float c = hist[(size_t)(SS + s) * (HH * BB) + i];
        m = fmaxf(m, tanhf(a * c));
    }
    pooled[i] = m;
}

__global__ __launch_bounds__(256)
void outgemm_k(const float* __restrict__ pooled, const float* __restrict__ Wout,
               const float* __restrict__ bout, float* __restrict__ out)
{
    const int c   = blockIdx.x;
    const int tid = threadIdx.x;
    const int b   = tid & 63;
    const int q   = __builtin_amdgcn_readfirstlane(tid >> 6);
    float p = 0.0f;
    for (int j = 0; j < 128; ++j) {
        const int h = q * 128 + j;
        p = fmaf(pooled[(size_t)h * BB + b], Wout[c * HH + h], p);
    }
    __shared__ float red[4][BB];
    red[q][b] = p;
    __syncthreads();
    if (tid < BB)
        out[tid * CC + c] = red[0][tid] + red[1][tid] + red[2][tid] + red[3][tid] + bout[c];
}

// ---------------------------------------------------------------------------
extern "C" void kernel_launch(void* const* d_in, const int* in_sizes, int n_in,
                              void* d_out, int out_size, void* d_ws, size_t ws_size,
                              hipStream_t stream)
{
    const int*   x     = (const int*)d_in[0];
    const float* embed = (const float*)d_in[1];
    const float* fwd_W = (const float*)d_in[2];
    const float* fwd_b = (const float*)d_in[3];
    const float* bwd_W = (const float*)d_in[4];
    const float* bwd_b = (const float*)d_in[5];
    const float* Wout  = (const float*)d_in[6];
    const float* bout  = (const float*)d_in[7];
    float* out = (float*)d_out;

    char* wsb = (char*)d_ws;
    short*    xef    = (short*)(wsb + OFF_XEF);
    short*    hspl   = (short*)(wsb + OFF_HSPL);
    unsigned* flg    = (unsigned*)(wsb + OFF_FLG);
    float*    hist   = (float*)(wsb + OFF_HIST);
    float*    pooled = (float*)(wsb + OFF_POOLED);   // overlays hspl (dead)

    gather_split_k<<<SS, 256, 0, stream>>>(x, embed, xef);
    zero_k<<<512, 256, 0, stream>>>((unsigned*)(wsb + OFF_HSPL),
                                    (int)((524288 + 1024) / 4));

    hipFuncSetAttribute((const void*)bilstm_recur_k,
                        hipFuncAttributeMaxDynamicSharedMemorySize, 136192);
    void* args[] = {(void*)&xef, (void*)&fwd_W, (void*)&bwd_W,
                    (void*)&fwd_b, (void*)&bwd_b,
                    (void*)&hspl, (void*)&hist, (void*)&flg};
    hipLaunchCooperativeKernel((void*)bilstm_recur_k, dim3(256), dim3(256),
                               args, 136192, stream);

    pool_k<<<128, 256, 0, stream>>>(hist, pooled);
    outgemm_k<<<CC, 256, 0, stream>>>(pooled, Wout, bout, out);
}

// Round 12
// 2147.018 us; speedup vs baseline: 1.5271x; 1.0568x over previous
//
#include <hip/hip_runtime.h>
#include <math.h>

#define HH 512
#define DD 512
#define BB 64
#define SS 256
#define KK 1024
#define CC 5

typedef __attribute__((ext_vector_type(8))) short short8;
typedef __attribute__((ext_vector_type(4))) float float4v;

// ---- workspace layout (bytes) ----  total used 100,926,464 (<= 101,188,608)
#define OFF_XEF     0u               // 256 s x 2 sp x 64 b x 512 k shorts = 33.5 MB
#define OFF_ROT     33554432u        // 257 slots x 256KB: [t][plane][dir][b][h] bf16
#define ROT_SLOT_B  262144u          // bytes per slot
#define OFF_FLG     100925440u       // 256 x 4B flags
#define OFF_POOLED  0u               // pooled overlays xef (dead after recurrence)

__device__ __forceinline__ unsigned f2bf_bits(float f) {
    unsigned u = __builtin_bit_cast(unsigned, f);
    return (u + 0x7fffu + ((u >> 16) & 1u)) >> 16;   // RNE
}
__device__ __forceinline__ float sigm_(float v) {
    return 1.f / (1.f + expf(-v));
}
__device__ __forceinline__ float tanh_(float v) {
    return tanhf(v);
}

// ---------------------------------------------------------------------------
// Gather embeddings + split hi/lo bf16 into xef[s][sp][b][k].
// ---------------------------------------------------------------------------
__global__ __launch_bounds__(256)
void gather_split_k(const int* __restrict__ x, const float* __restrict__ embed,
                    short* __restrict__ xef)
{
    const int s   = blockIdx.x;
    const int tid = threadIdx.x;
    const int b   = tid & 63;
    const int seg = tid >> 6;            // 4 segs x 128 k
    __shared__ int rows[BB];
    if (tid < BB) rows[tid] = x[tid * SS + s];   // x is [B][S]
    __syncthreads();
    const float* e = embed + (size_t)rows[b] * DD + seg * 128;
    short* oh = xef + ((size_t)(s * 2 + 0) * BB + b) * 512 + seg * 128;
    short* ol = xef + ((size_t)(s * 2 + 1) * BB + b) * 512 + seg * 128;
    for (int k0 = 0; k0 < 128; k0 += 8) {
        const float4 a = *(const float4*)(e + k0);
        const float4 c = *(const float4*)(e + k0 + 4);
        const float ev[8] = {a.x, a.y, a.z, a.w, c.x, c.y, c.z, c.w};
        short8 vh, vl;
        #pragma unroll
        for (int j = 0; j < 8; ++j) {
            const unsigned hib = f2bf_bits(ev[j]);
            const float hif = __builtin_bit_cast(float, hib << 16);
            const unsigned lob = f2bf_bits(ev[j] - hif);
            vh[j] = (short)hib;
            vl[j] = (short)lob;
        }
        *(short8*)(oh + k0) = vh;
        *(short8*)(ol + k0) = vl;
    }
}

// ---------------------------------------------------------------------------
__global__ __launch_bounds__(256)
void zero_k(unsigned* __restrict__ base, int ndw)
{
    int i = blockIdx.x * 256 + threadIdx.x;
    const int stride = gridDim.x * 256;
    for (; i < ndw; i += stride) base[i] = 0u;
}

// ---------------------------------------------------------------------------
// Cooperative recurrence: 256 WGs x 256 thr (1 WG/CU). R19 = R11-proven body
// with the h broadcast made L2-SHAREABLE:
//   - h lives in a ROTATING buffer of 257 fresh 256KB slots (publish slot
//     t+1, consume slot t; slot 0 zeroed). Within the launch no consumer L2
//     can hold a stale copy of a slot line (first touch is always after the
//     slot is fully published); across launches, dispatch-acquire
//     invalidates L2 (same mechanism that makes plain xef reads correct).
//   - consumer staging loads become PLAIN 16B loads -> 16 WGs/XCD share one
//     LLC fetch via L2 (32 MB/step bypass traffic -> ~2 MB/step LLC + L2
//     hits), and per-WG line count halves again (2048 -> 1024).
//   - producers keep agent-scope write-through stores + flag protocol
//     BYTE-IDENTICAL to R11 (only the destination address changed).
//   - hist is eliminated (rot replaces it; pool_k reconstructs h = hi+lo).
// x-part, spin, exchange, gates, publish structure: byte-identical to R11.
// ---------------------------------------------------------------------------
__global__ void __launch_bounds__(256, 1)
bilstm_recur_k(const short* __restrict__ xef,
               const float* __restrict__ fwd_W, const float* __restrict__ bwd_W,
               const float* __restrict__ fwd_b, const float* __restrict__ bwd_b,
               short* __restrict__ rot, unsigned* __restrict__ flg)
{
    extern __shared__ char smem[];
    short8* wlds = (short8*)smem;                           // 64 KB W fragments
    char*   hbuf = smem + 65536;                            // 64 KB staged h plane
    float*  ex   = (float*)(smem + 131072);                 // 4 KB exchange
    unsigned short* stg = (unsigned short*)(smem + 135168); // 1 KB publish stage

    const int w      = blockIdx.x;
    const int dir    = w >> 7;
    const int wlocal = w & 127;
    const int h0     = wlocal << 2;
    const int tid    = threadIdx.x;
    const int lane   = tid & 63;
    const int wv     = __builtin_amdgcn_readfirstlane(tid >> 6);
    const int n0     = wv << 4;
    const int nn     = lane & 15;
    const int quad   = lane >> 4;

    // ---- pack this WG's W fragments straight into LDS (bit-identical to
    //      wpack_k: f2bf_bits split of W[(g*H+h0+hh)][kt*32+quad*8+j]) ----
    {
        const float* W = dir ? bwd_W : fwd_W;
        const int m  = lane & 15;
        const int g  = m >> 2;
        const int hh = m & 3;
        const float* wrow = W + ((size_t)g * HH + h0 + hh) * KK + quad * 8;
        for (int kk = 0; kk < 8; ++kk) {
            const int kt = wv * 8 + kk;          // 4 waves x 8 = 32 kt
            const float4 a  = *(const float4*)(wrow + kt * 32);
            const float4 c4 = *(const float4*)(wrow + kt * 32 + 4);
            const float ev[8] = {a.x, a.y, a.z, a.w, c4.x, c4.y, c4.z, c4.w};
            short8 vh, vl;
            #pragma unroll
            for (int j = 0; j < 8; ++j) {
                const unsigned hib = f2bf_bits(ev[j]);
                const float hif = __builtin_bit_cast(float, hib << 16);
                const unsigned lob = f2bf_bits(ev[j] - hif);
                vh[j] = (short)hib;
                vl[j] = (short)lob;
            }
            wlds[(0 * 32 + kt) * 64 + lane] = vh;
            wlds[(1 * 32 + kt) * 64 + lane] = vl;
        }
    }
    __syncthreads();

    const float* bi = dir ? bwd_b : fwd_b;
    const float4 biasv = *(const float4*)(bi + quad * HH + h0);
    const float bias_arr[4] = {biasv.x, biasv.y, biasv.z, biasv.w};

    unsigned* myflg = flg + dir * 128;
    float* exw = ex + wv * 256;
    const int b = n0 + nn;

    for (int t = 0; t < SS; ++t) {
        const int s = dir ? (SS - 1 - t) : t;

        float4v acc = {0.f, 0.f, 0.f, 0.f};

        // ---------- x-part: contiguous fragment loads from xef ----------
        {
            const short8* xh8 = (const short8*)(xef +
                ((size_t)(s * 2 + 0) * BB + b) * 512 + quad * 8);
            const short8* xl8 = (const short8*)(xef +
                ((size_t)(s * 2 + 1) * BB + b) * 512 + quad * 8);
            #pragma unroll
            for (int kt = 0; kt < 16; ++kt) {
                const short8 xh  = xh8[kt * 4];
                const short8 xl  = xl8[kt * 4];
                const short8 whi = wlds[(0 * 32 + kt) * 64 + lane];
                const short8 wlo = wlds[(1 * 32 + kt) * 64 + lane];
                acc = __builtin_amdgcn_mfma_f32_16x16x32_bf16(whi, xh, acc, 0, 0, 0);
                acc = __builtin_amdgcn_mfma_f32_16x16x32_bf16(whi, xl, acc, 0, 0, 0);
                acc = __builtin_amdgcn_mfma_f32_16x16x32_bf16(wlo, xh, acc, 0, 0, 0);
            }
        }

        // ---------- wait: all WGs of this dir finished step t-1 ----------
        if (t > 0) {
            const unsigned tgt = (unsigned)t;
            unsigned va, vb;
            va = __hip_atomic_load(myflg + lane, __ATOMIC_RELAXED,
                                   __HIP_MEMORY_SCOPE_AGENT);
            vb = __hip_atomic_load(myflg + 64 + lane, __ATOMIC_RELAXED,
                                   __HIP_MEMORY_SCOPE_AGENT);
            while (__any(va < tgt || vb < tgt)) {
                __builtin_amdgcn_s_sleep(32);
                va = __hip_atomic_load(myflg + lane, __ATOMIC_RELAXED,
                                       __HIP_MEMORY_SCOPE_AGENT);
                vb = __hip_atomic_load(myflg + 64 + lane, __ATOMIC_RELAXED,
                                       __HIP_MEMORY_SCOPE_AGENT);
            }
            asm volatile("" ::: "memory");
        }

        // ---------- h-part: PLAIN coalesced 16B stage -> LDS -> MFMA ------
        {
            const char* slot = (const char*)rot + (size_t)t * ROT_SLOT_B
                             + (size_t)dir * 65536;
            const short8* hq = (const short8*)(slot);            // hi plane
            const short8* lq = (const short8*)(slot + 131072);   // lo plane

            short8 sh[16], sl[16];
            #pragma unroll
            for (int it = 0; it < 16; ++it)
                sh[it] = hq[it * 256 + tid];
            #pragma unroll
            for (int it = 0; it < 16; ++it)
                sl[it] = lq[it * 256 + tid];

            const int kb = (tid & 63) * 16;
            const int bbb = tid >> 6;

            // ---- hi plane into swizzled LDS ----
            #pragma unroll
            for (int it = 0; it < 16; ++it) {
                const int bb = it * 4 + bbb;
                *(short8*)(hbuf + ((bb << 10) | (kb ^ ((bb & 7) << 4)))) = sh[it];
            }
            __syncthreads();
            #pragma unroll
            for (int kt = 0; kt < 16; ++kt) {
                const short8 uh = *(const short8*)(hbuf + ((b << 10) |
                    ((quad * 16 + kt * 64) ^ ((b & 7) << 4))));
                const short8 whi = wlds[(0 * 32 + 16 + kt) * 64 + lane];
                const short8 wlo = wlds[(1 * 32 + 16 + kt) * 64 + lane];
                acc = __builtin_amdgcn_mfma_f32_16x16x32_bf16(whi, uh, acc, 0, 0, 0);
                acc = __builtin_amdgcn_mfma_f32_16x16x32_bf16(wlo, uh, acc, 0, 0, 0);
            }
            __syncthreads();

            // ---- lo plane into swizzled LDS ----
            #pragma unroll
            for (int it = 0; it < 16; ++it) {
                const int bb = it * 4 + bbb;
                *(short8*)(hbuf + ((bb << 10) | (kb ^ ((bb & 7) << 4)))) = sl[it];
            }
            __syncthreads();
            #pragma unroll
            for (int kt = 0; kt < 16; ++kt) {
                const short8 ul = *(const short8*)(hbuf + ((b << 10) |
                    ((quad * 16 + kt * 64) ^ ((b & 7) << 4))));
                const short8 whi = wlds[(0 * 32 + 16 + kt) * 64 + lane];
                acc = __builtin_amdgcn_mfma_f32_16x16x32_bf16(whi, ul, acc, 0, 0, 0);
            }
        }

        // ---------- bias + per-wave exchange ----------
        #pragma unroll
        for (int r2 = 0; r2 < 4; ++r2)
            exw[(quad * 4 + r2) * 16 + nn] = acc[r2] + bias_arr[r2];
        float pg[4];
        #pragma unroll
        for (int g_ = 0; g_ < 4; ++g_)
            pg[g_] = exw[(g_ * 4 + quad) * 16 + nn];

        const float f_  = sigm_(pg[0]);
        const float i_  = sigm_(pg[1]);
        const float ct  = tanh_(pg[2]);
        const float o_  = sigm_(pg[3]);
        const float c_  = (f_ + i_) * ct;      // faithful: prev cell unused
        const float hn  = o_ * tanh_(c_);

        const unsigned hib = f2bf_bits(hn);
        const float hif = __builtin_bit_cast(float, hib << 16);
        const unsigned lob = f2bf_bits(hn - hif);
        stg[(0 * 4 + quad) * 64 + b] = (unsigned short)hib;
        stg[(1 * 4 + quad) * 64 + b] = (unsigned short)lob;
        __syncthreads();

        // ---------- publish into rot slot t+1 (agent write-through) ------
        {
            const int plane = tid >> 7;          // 0 hi, 1 lo
            const int d     = tid & 127;
            const int pb    = d >> 1;
            const int pair  = d & 1;
            const unsigned v0 = stg[(plane * 4 + pair * 2 + 0) * 64 + pb];
            const unsigned v1 = stg[(plane * 4 + pair * 2 + 1) * 64 + pb];
            const unsigned val = v0 | (v1 << 16);
            const size_t so = (size_t)(t + 1) * 131072 + (size_t)plane * 65536
                            + (size_t)dir * 32768 + (size_t)pb * 512
                            + h0 + pair * 2;             // short index
            unsigned* dst = (unsigned*)(rot + so);
            __hip_atomic_store(dst, val, __ATOMIC_RELAXED,
                               __HIP_MEMORY_SCOPE_AGENT);
        }
        asm volatile("s_waitcnt vmcnt(0)" ::: "memory");
        __syncthreads();
        if (tid == 0)
            __hip_atomic_store(myflg + wlocal, (unsigned)(t + 1),
                               __ATOMIC_RELAXED, __HIP_MEMORY_SCOPE_AGENT);
    }
}

// ---------------------------------------------------------------------------
// Pool from the rotation buffer: reconstruct h = hi + lo (error ~1e-5, well
// under the 2.94e-4 threshold; recurrence numerics are unchanged since MFMA
// always consumed exactly these hi/lo splits).
// ---------------------------------------------------------------------------
__global__ __launch_bounds__(256)
void pool_k(const short* __restrict__ rot, float* __restrict__ pooled)
{
    const int tg = blockIdx.x * 256 + threadIdx.x;   // 32768 = 64 b x 512 h
    const int b  = tg >> 9;
    const int h  = tg & 511;
    const int off = b * 512 + h;
    float m = -2.0f;
    for (int s = 0; s < SS; ++s) {
        const short* fs = rot + (size_t)(s + 1) * 131072;
        const short* bs = rot + (size_t)(SS - s) * 131072;
        const unsigned hf = (unsigned short)fs[off];             // plane0 dir0
        const unsigned lf = (unsigned short)fs[65536 + off];     // plane1 dir0
        const unsigned hb = (unsigned short)bs[32768 + off];     // plane0 dir1
        const unsigned lb = (unsigned short)bs[65536 + 32768 + off];
        const float af = __builtin_bit_cast(float, hf << 16)
                       + __builtin_bit_cast(float, lf << 16);
        const float ab = __builtin_bit_cast(float, hb << 16)
                       + __builtin_bit_cast(float, lb << 16);
        m = fmaxf(m, tanhf(af * ab));
    }
    pooled[(size_t)h * BB + b] = m;
}

__global__ __launch_bounds__(256)
void outgemm_k(const float* __restrict__ pooled, const float* __restrict__ Wout,
               const float* __restrict__ bout, float* __restrict__ out)
{
    const int c   = blockIdx.x;
    const int tid = threadIdx.x;
    const int b   = tid & 63;
    const int q   = __builtin_amdgcn_readfirstlane(tid >> 6);
    float p = 0.0f;
    for (int j = 0; j < 128; ++j) {
        const int h = q * 128 + j;
        p = fmaf(pooled[(size_t)h * BB + b], Wout[c * HH + h], p);
    }
    __shared__ float red[4][BB];
    red[q][b] = p;
    __syncthreads();
    if (tid < BB)
        out[tid * CC + c] = red[0][tid] + red[1][tid] + red[2][tid] + red[3][tid] + bout[c];
}

// ---------------------------------------------------------------------------
extern "C" void kernel_launch(void* const* d_in, const int* in_sizes, int n_in,
                              void* d_out, int out_size, void* d_ws, size_t ws_size,
                              hipStream_t stream)
{
    const int*   x     = (const int*)d_in[0];
    const float* embed = (const float*)d_in[1];
    const float* fwd_W = (const float*)d_in[2];
    const float* fwd_b = (const float*)d_in[3];
    const float* bwd_W = (const float*)d_in[4];
    const float* bwd_b = (const float*)d_in[5];
    const float* Wout  = (const float*)d_in[6];
    const float* bout  = (const float*)d_in[7];
    float* out = (float*)d_out;

    char* wsb = (char*)d_ws;
    short*    xef    = (short*)(wsb + OFF_XEF);
    short*    rot    = (short*)(wsb + OFF_ROT);
    unsigned* flg    = (unsigned*)(wsb + OFF_FLG);
    float*    pooled = (float*)(wsb + OFF_POOLED);   // overlays xef (dead)

    gather_split_k<<<SS, 256, 0, stream>>>(x, embed, xef);
    zero_k<<<64, 256, 0, stream>>>((unsigned*)(wsb + OFF_ROT),
                                   (int)(ROT_SLOT_B / 4));   // slot 0
    zero_k<<<1, 256, 0, stream>>>(flg, 256);                 // flags

    hipFuncSetAttribute((const void*)bilstm_recur_k,
                        hipFuncAttributeMaxDynamicSharedMemorySize, 136192);
    void* args[] = {(void*)&xef, (void*)&fwd_W, (void*)&bwd_W,
                    (void*)&fwd_b, (void*)&bwd_b,
                    (void*)&rot, (void*)&flg};
    hipLaunchCooperativeKernel((void*)bilstm_recur_k, dim3(256), dim3(256),
                               args, 136192, stream);

    pool_k<<<128, 256, 0, stream>>>(rot, pooled);
    outgemm_k<<<CC, 256, 0, stream>>>(pooled, Wout, bout, out);
}

// Round 13
// 2034.056 us; speedup vs baseline: 1.6119x; 1.0555x over previous
//
#include <hip/hip_runtime.h>
#include <math.h>

#define HH 512
#define DD 512
#define BB 64
#define SS 256
#define KK 1024
#define CC 5

typedef __attribute__((ext_vector_type(8))) short short8;
typedef __attribute__((ext_vector_type(4))) float float4v;

// ---- workspace layout (bytes) ----  total used 100,926,464 (<= 101,188,608)
#define OFF_XEF     0u               // 256 s x 2 sp x 64 b x 512 k shorts = 33.5 MB
#define OFF_ROT     33554432u        // 257 slots x 256KB: [t][plane][dir][b][h] bf16
#define ROT_SLOT_B  262144u          // bytes per slot
#define OFF_FLG     100925440u       // 256 x 4B flags
#define OFF_POOLED  0u               // pooled overlays xef (dead after recurrence)

__device__ __forceinline__ unsigned f2bf_bits(float f) {
    unsigned u = __builtin_bit_cast(unsigned, f);
    return (u + 0x7fffu + ((u >> 16) & 1u)) >> 16;   // RNE
}
__device__ __forceinline__ float sigm_(float v) {
    return 1.f / (1.f + expf(-v));
}
__device__ __forceinline__ float tanh_(float v) {
    return tanhf(v);
}

// ---------------------------------------------------------------------------
// Gather embeddings + split hi/lo bf16 into xef[s][sp][b][k].
// ---------------------------------------------------------------------------
__global__ __launch_bounds__(256)
void gather_split_k(const int* __restrict__ x, const float* __restrict__ embed,
                    short* __restrict__ xef)
{
    const int s   = blockIdx.x;
    const int tid = threadIdx.x;
    const int b   = tid & 63;
    const int seg = tid >> 6;            // 4 segs x 128 k
    __shared__ int rows[BB];
    if (tid < BB) rows[tid] = x[tid * SS + s];   // x is [B][S]
    __syncthreads();
    const float* e = embed + (size_t)rows[b] * DD + seg * 128;
    short* oh = xef + ((size_t)(s * 2 + 0) * BB + b) * 512 + seg * 128;
    short* ol = xef + ((size_t)(s * 2 + 1) * BB + b) * 512 + seg * 128;
    for (int k0 = 0; k0 < 128; k0 += 8) {
        const float4 a = *(const float4*)(e + k0);
        const float4 c = *(const float4*)(e + k0 + 4);
        const float ev[8] = {a.x, a.y, a.z, a.w, c.x, c.y, c.z, c.w};
        short8 vh, vl;
        #pragma unroll
        for (int j = 0; j < 8; ++j) {
            const unsigned hib = f2bf_bits(ev[j]);
            const float hif = __builtin_bit_cast(float, hib << 16);
            const unsigned lob = f2bf_bits(ev[j] - hif);
            vh[j] = (short)hib;
            vl[j] = (short)lob;
        }
        *(short8*)(oh + k0) = vh;
        *(short8*)(ol + k0) = vl;
    }
}

// ---------------------------------------------------------------------------
__global__ __launch_bounds__(256)
void zero_k(unsigned* __restrict__ base, int ndw)
{
    int i = blockIdx.x * 256 + threadIdx.x;
    const int stride = gridDim.x * 256;
    for (; i < ndw; i += stride) base[i] = 0u;
}

// ---------------------------------------------------------------------------
// Cooperative recurrence: 256 WGs x 256 thr (1 WG/CU). R20 = R12-proven body
// de-barriered: every cross-wave sync that guarded per-wave-independent work
// is made WAVE-LOCAL (5 -> 1 __syncthreads per step):
//   - h staging: wave wv stages ONLY its own 16 LDS rows (n0..n0+15), still
//     perfectly coalesced (contiguous 16KB span); stage->MFMA dependency is
//     within-wave (lgkmcnt), no barriers; lo-plane restages the same rows
//     after the hi MFMAs drain (within-wave WAR, compiler-ordered).
//   - publish exchange: per-wave stg regions (thread (quad,nn) and the
//     packed-dword publisher for b in [n0,n0+16) are the SAME wave) — the
//     wave-synchronous LDS pattern exw already uses.
//   - ONE barrier remains: all waves' publishes vmcnt-acked before the flag.
// Arithmetic is bit-identical to R12 (same fragments, same MFMA order, same
// publish addresses). Rotation buffer / L2-sharing / flag protocol unchanged.
// ---------------------------------------------------------------------------
__global__ void __launch_bounds__(256, 1)
bilstm_recur_k(const short* __restrict__ xef,
               const float* __restrict__ fwd_W, const float* __restrict__ bwd_W,
               const float* __restrict__ fwd_b, const float* __restrict__ bwd_b,
               short* __restrict__ rot, unsigned* __restrict__ flg)
{
    extern __shared__ char smem[];
    short8* wlds = (short8*)smem;                           // 64 KB W fragments
    char*   hbuf = smem + 65536;                            // 64 KB staged h plane
    float*  ex   = (float*)(smem + 131072);                 // 4 KB exchange
    unsigned short* stg = (unsigned short*)(smem + 135168); // 1 KB publish stage

    const int w      = blockIdx.x;
    const int dir    = w >> 7;
    const int wlocal = w & 127;
    const int h0     = wlocal << 2;
    const int tid    = threadIdx.x;
    const int lane   = tid & 63;
    const int wv     = __builtin_amdgcn_readfirstlane(tid >> 6);
    const int n0     = wv << 4;
    const int nn     = lane & 15;
    const int quad   = lane >> 4;

    // ---- pack this WG's W fragments straight into LDS (bit-identical to
    //      wpack_k: f2bf_bits split of W[(g*H+h0+hh)][kt*32+quad*8+j]) ----
    {
        const float* W = dir ? bwd_W : fwd_W;
        const int m  = lane & 15;
        const int g  = m >> 2;
        const int hh = m & 3;
        const float* wrow = W + ((size_t)g * HH + h0 + hh) * KK + quad * 8;
        for (int kk = 0; kk < 8; ++kk) {
            const int kt = wv * 8 + kk;          // 4 waves x 8 = 32 kt
            const float4 a  = *(const float4*)(wrow + kt * 32);
            const float4 c4 = *(const float4*)(wrow + kt * 32 + 4);
            const float ev[8] = {a.x, a.y, a.z, a.w, c4.x, c4.y, c4.z, c4.w};
            short8 vh, vl;
            #pragma unroll
            for (int j = 0; j < 8; ++j) {
                const unsigned hib = f2bf_bits(ev[j]);
                const float hif = __builtin_bit_cast(float, hib << 16);
                const unsigned lob = f2bf_bits(ev[j] - hif);
                vh[j] = (short)hib;
                vl[j] = (short)lob;
            }
            wlds[(0 * 32 + kt) * 64 + lane] = vh;
            wlds[(1 * 32 + kt) * 64 + lane] = vl;
        }
    }
    __syncthreads();

    const float* bi = dir ? bwd_b : fwd_b;
    const float4 biasv = *(const float4*)(bi + quad * HH + h0);
    const float bias_arr[4] = {biasv.x, biasv.y, biasv.z, biasv.w};

    unsigned* myflg = flg + dir * 128;
    float* exw = ex + wv * 256;
    unsigned short* stgw = stg + wv * 128;   // per-wave publish stage
    const int b = n0 + nn;

    for (int t = 0; t < SS; ++t) {
        const int s = dir ? (SS - 1 - t) : t;

        float4v acc = {0.f, 0.f, 0.f, 0.f};

        // ---------- x-part: contiguous fragment loads from xef ----------
        {
            const short8* xh8 = (const short8*)(xef +
                ((size_t)(s * 2 + 0) * BB + b) * 512 + quad * 8);
            const short8* xl8 = (const short8*)(xef +
                ((size_t)(s * 2 + 1) * BB + b) * 512 + quad * 8);
            #pragma unroll
            for (int kt = 0; kt < 16; ++kt) {
                const short8 xh  = xh8[kt * 4];
                const short8 xl  = xl8[kt * 4];
                const short8 whi = wlds[(0 * 32 + kt) * 64 + lane];
                const short8 wlo = wlds[(1 * 32 + kt) * 64 + lane];
                acc = __builtin_amdgcn_mfma_f32_16x16x32_bf16(whi, xh, acc, 0, 0, 0);
                acc = __builtin_amdgcn_mfma_f32_16x16x32_bf16(whi, xl, acc, 0, 0, 0);
                acc = __builtin_amdgcn_mfma_f32_16x16x32_bf16(wlo, xh, acc, 0, 0, 0);
            }
        }

        // ---------- wait: all WGs of this dir finished step t-1 ----------
        if (t > 0) {
            const unsigned tgt = (unsigned)t;
            unsigned va, vb;
            va = __hip_atomic_load(myflg + lane, __ATOMIC_RELAXED,
                                   __HIP_MEMORY_SCOPE_AGENT);
            vb = __hip_atomic_load(myflg + 64 + lane, __ATOMIC_RELAXED,
                                   __HIP_MEMORY_SCOPE_AGENT);
            while (__any(va < tgt || vb < tgt)) {
                __builtin_amdgcn_s_sleep(32);
                va = __hip_atomic_load(myflg + lane, __ATOMIC_RELAXED,
                                       __HIP_MEMORY_SCOPE_AGENT);
                vb = __hip_atomic_load(myflg + 64 + lane, __ATOMIC_RELAXED,
                                       __HIP_MEMORY_SCOPE_AGENT);
            }
            asm volatile("" ::: "memory");
        }

        // ---------- h-part: per-wave coalesced stage -> own LDS rows ------
        {
            const char* slot = (const char*)rot + (size_t)t * ROT_SLOT_B
                             + (size_t)dir * 65536;
            const short8* hq = (const short8*)(slot);            // hi plane
            const short8* lq = (const short8*)(slot + 131072);   // lo plane

            short8 sh[16], sl[16];
            #pragma unroll
            for (int it = 0; it < 16; ++it)
                sh[it] = hq[(n0 + it) * 64 + lane];
            #pragma unroll
            for (int it = 0; it < 16; ++it)
                sl[it] = lq[(n0 + it) * 64 + lane];

            // ---- hi plane into own swizzled rows (wave-synchronous) ----
            #pragma unroll
            for (int it = 0; it < 16; ++it) {
                const int r = n0 + it;
                *(short8*)(hbuf + ((r << 10) |
                    ((lane * 16) ^ ((r & 7) << 4)))) = sh[it];
            }
            #pragma unroll
            for (int kt = 0; kt < 16; ++kt) {
                const short8 uh = *(const short8*)(hbuf + ((b << 10) |
                    ((quad * 16 + kt * 64) ^ ((b & 7) << 4))));
                const short8 whi = wlds[(0 * 32 + 16 + kt) * 64 + lane];
                const short8 wlo = wlds[(1 * 32 + 16 + kt) * 64 + lane];
                acc = __builtin_amdgcn_mfma_f32_16x16x32_bf16(whi, uh, acc, 0, 0, 0);
                acc = __builtin_amdgcn_mfma_f32_16x16x32_bf16(wlo, uh, acc, 0, 0, 0);
            }

            // ---- lo plane reuses the same rows (within-wave WAR) ----
            #pragma unroll
            for (int it = 0; it < 16; ++it) {
                const int r = n0 + it;
                *(short8*)(hbuf + ((r << 10) |
                    ((lane * 16) ^ ((r & 7) << 4)))) = sl[it];
            }
            #pragma unroll
            for (int kt = 0; kt < 16; ++kt) {
                const short8 ul = *(const short8*)(hbuf + ((b << 10) |
                    ((quad * 16 + kt * 64) ^ ((b & 7) << 4))));
                const short8 whi = wlds[(0 * 32 + 16 + kt) * 64 + lane];
                acc = __builtin_amdgcn_mfma_f32_16x16x32_bf16(whi, ul, acc, 0, 0, 0);
            }
        }

        // ---------- bias + per-wave exchange ----------
        #pragma unroll
        for (int r2 = 0; r2 < 4; ++r2)
            exw[(quad * 4 + r2) * 16 + nn] = acc[r2] + bias_arr[r2];
        float pg[4];
        #pragma unroll
        for (int g_ = 0; g_ < 4; ++g_)
            pg[g_] = exw[(g_ * 4 + quad) * 16 + nn];

        const float f_  = sigm_(pg[0]);
        const float i_  = sigm_(pg[1]);
        const float ct  = tanh_(pg[2]);
        const float o_  = sigm_(pg[3]);
        const float c_  = (f_ + i_) * ct;      // faithful: prev cell unused
        const float hn  = o_ * tanh_(c_);

        const unsigned hib = f2bf_bits(hn);
        const float hif = __builtin_bit_cast(float, hib << 16);
        const unsigned lob = f2bf_bits(hn - hif);
        // per-wave stage: [plane][quad][nn]
        stgw[0 * 64 + quad * 16 + nn] = (unsigned short)hib;
        stgw[1 * 64 + quad * 16 + nn] = (unsigned short)lob;

        // ---------- publish into rot slot t+1 (per-wave, agent stores) ----
        {
            const int pl   = lane >> 5;          // 0 hi, 1 lo
            const int pair = (lane >> 4) & 1;
            const int n2   = lane & 15;
            const int pb   = n0 + n2;
            const unsigned v0 = stgw[pl * 64 + (pair * 2 + 0) * 16 + n2];
            const unsigned v1 = stgw[pl * 64 + (pair * 2 + 1) * 16 + n2];
            const unsigned val = v0 | (v1 << 16);
            const size_t so = (size_t)(t + 1) * 131072 + (size_t)pl * 65536
                            + (size_t)dir * 32768 + (size_t)pb * 512
                            + h0 + pair * 2;             // short index
            unsigned* dst = (unsigned*)(rot + so);
            __hip_atomic_store(dst, val, __ATOMIC_RELAXED,
                               __HIP_MEMORY_SCOPE_AGENT);
        }
        asm volatile("s_waitcnt vmcnt(0)" ::: "memory");
        __syncthreads();        // sole barrier: all publishes acked
        if (tid == 0)
            __hip_atomic_store(myflg + wlocal, (unsigned)(t + 1),
                               __ATOMIC_RELAXED, __HIP_MEMORY_SCOPE_AGENT);
    }
}

// ---------------------------------------------------------------------------
// Pool from the rotation buffer: reconstruct h = hi + lo (error ~1e-5, well
// under the 2.94e-4 threshold; recurrence numerics are unchanged since MFMA
// always consumed exactly these hi/lo splits).
// ---------------------------------------------------------------------------
__global__ __launch_bounds__(256)
void pool_k(const short* __restrict__ rot, float* __restrict__ pooled)
{
    const int tg = blockIdx.x * 256 + threadIdx.x;   // 32768 = 64 b x 512 h
    const int b  = tg >> 9;
    const int h  = tg & 511;
    const int off = b * 512 + h;
    float m = -2.0f;
    for (int s = 0; s < SS; ++s) {
        const short* fs = rot + (size_t)(s + 1) * 131072;
        const short* bs = rot + (size_t)(SS - s) * 131072;
        const unsigned hf = (unsigned short)fs[off];             // plane0 dir0
        const unsigned lf = (unsigned short)fs[65536 + off];     // plane1 dir0
        const unsigned hb = (unsigned short)bs[32768 + off];     // plane0 dir1
        const unsigned lb = (unsigned short)bs[65536 + 32768 + off];
        const float af = __builtin_bit_cast(float, hf << 16)
                       + __builtin_bit_cast(float, lf << 16);
        const float ab = __builtin_bit_cast(float, hb << 16)
                       + __builtin_bit_cast(float, lb << 16);
        m = fmaxf(m, tanhf(af * ab));
    }
    pooled[(size_t)h * BB + b] = m;
}

__global__ __launch_bounds__(256)
void outgemm_k(const float* __restrict__ pooled, const float* __restrict__ Wout,
               const float* __restrict__ bout, float* __restrict__ out)
{
    const int c   = blockIdx.x;
    const int tid = threadIdx.x;
    const int b   = tid & 63;
    const int q   = __builtin_amdgcn_readfirstlane(tid >> 6);
    float p = 0.0f;
    for (int j = 0; j < 128; ++j) {
        const int h = q * 128 + j;
        p = fmaf(pooled[(size_t)h * BB + b], Wout[c * HH + h], p);
    }
    __shared__ float red[4][BB];
    red[q][b] = p;
    __syncthreads();
    if (tid < BB)
        out[tid * CC + c] = red[0][tid] + red[1][tid] + red[2][tid] + red[3][tid] + bout[c];
}

// ---------------------------------------------------------------------------
extern "C" void kernel_launch(void* const* d_in, const int* in_sizes, int n_in,
                              void* d_out, int out_size, void* d_ws, size_t ws_size,
                              hipStream_t stream)
{
    const int*   x     = (const int*)d_in[0];
    const float* embed = (const float*)d_in[1];
    const float* fwd_W = (const float*)d_in[2];
    const float* fwd_b = (const float*)d_in[3];
    const float* bwd_W = (const float*)d_in[4];
    const float* bwd_b = (const float*)d_in[5];
    const float* Wout  = (const float*)d_in[6];
    const float* bout  = (const float*)d_in[7];
    float* out = (float*)d_out;

    char* wsb = (char*)d_ws;
    short*    xef    = (short*)(wsb + OFF_XEF);
    short*    rot    = (short*)(wsb + OFF_ROT);
    unsigned* flg    = (unsigned*)(wsb + OFF_FLG);
    float*    pooled = (float*)(wsb + OFF_POOLED);   // overlays xef (dead)

    gather_split_k<<<SS, 256, 0, stream>>>(x, embed, xef);
    zero_k<<<64, 256, 0, stream>>>((unsigned*)(wsb + OFF_ROT),
                                   (int)(ROT_SLOT_B / 4));   // slot 0
    zero_k<<<1, 256, 0, stream>>>(flg, 256);                 // flags

    hipFuncSetAttribute((const void*)bilstm_recur_k,
                        hipFuncAttributeMaxDynamicSharedMemorySize, 136192);
    void* args[] = {(void*)&xef, (void*)&fwd_W, (void*)&bwd_W,
                    (void*)&fwd_b, (void*)&bwd_b,
                    (void*)&rot, (void*)&flg};
    hipLaunchCooperativeKernel((void*)bilstm_recur_k, dim3(256), dim3(256),
                               args, 136192, stream);

    pool_k<<<128, 256, 0, stream>>>(rot, pooled);
    outgemm_k<<<CC, 256, 0, stream>>>(pooled, Wout, bout, out);
}